// Round 14
// baseline (100.830 us; speedup 1.0000x reference)
//
#include <hip/hip_runtime.h>
#include <hip/hip_bf16.h>

#define NN 16384
#define DD 64
#define NBI 32                 // 512-row bands
#define NUNITS 2112            // sum_I (128 - 4I), I=0..31
#define NBLK 512               // 512 blocks x 2/CU (56.4 KB LDS) -> all resident
#define SCREEN_T 0.49f         // hinge>0 needs gram > ~0.5-3e-5; margin 1e-2

constexpr float F_EPS_PD   = 1e-6f;
constexpr float F_EPS_NORM = 1e-6f;

using bf16x8 = __attribute__((ext_vector_type(8))) short;
using f32x4  = __attribute__((ext_vector_type(4))) float;
typedef __attribute__((address_space(1))) const unsigned int gu32_t;
typedef __attribute__((address_space(3))) unsigned int       lu32_t;

__device__ __forceinline__ float wave_sum_f(float v) {
    #pragma unroll
    for (int o = 32; o >= 1; o >>= 1) v += __shfl_xor(v, o);
    return v;
}

__device__ __forceinline__ int band_off(int I) { return 2 * I * (65 - I); }

// ---------------------------------------------------------------------------
// Stage one (B tile 16 KB + vcp slice 1 KB) into a ring slot. 3 ops per wave
// (uniform -> exact vmcnt counts). B source XOR-preswizzled (both-sides rule).
// ---------------------------------------------------------------------------
__device__ __forceinline__ void stage_tile(const short* ebf, const float2* vcp,
                                           int tile, short* slotB, float2* slotV,
                                           int w, int lane) {
    const short* tbase = ebf + (size_t)tile * (128 * DD);
    int rlo = lane >> 3;
    int g   = (lane & 7) ^ rlo;
    #pragma unroll
    for (int q = 0; q < 2; ++q) {
        int m = w * 2 + q;
        __builtin_amdgcn_global_load_lds(
            (gu32_t*)(const void*)(tbase + (size_t)(8 * m + rlo) * DD + g * 8),
            (lu32_t*)(void*)(slotB + m * 512), 16, 0, 0);
    }
    __builtin_amdgcn_global_load_lds(
        (gu32_t*)(const void*)(vcp + (size_t)tile * 128 + lane * 2),
        (lu32_t*)(void*)slotV, 16, 0, 0);
}

// ---------------------------------------------------------------------------
// Fused kernel: phase 1 norm -> device spin-barrier -> phase 2 pair (R8 core
// verbatim: counted-vmcnt 3-slot ring, 2-deep prefetch, zero vmem in compute)
// -> block-0-only wait -> phase 3 reduce. Co-residency: 512 blocks, 56.4 KB
// LDS each = exactly 2/CU on 256 CUs (pigeonhole). Cross-XCD visibility via
// __hip_atomic release/acquire at AGENT scope (wbl2/inv). Counters zeroed by
// stream-ordered 8-byte memset before launch (graph-legal).
// ---------------------------------------------------------------------------
__global__ __launch_bounds__(512, 4) void fused_kernel(
    const float* __restrict__ emb, const int* __restrict__ pidx,
    const int* __restrict__ lab, float2* __restrict__ up,
    float2* __restrict__ vcp, __hip_bfloat16* __restrict__ ebf,
    float* __restrict__ posP, float* __restrict__ negP,
    unsigned int* cnt, float* __restrict__ out) {
    __shared__ short  ringB[3][8192];   // 3 x 16 KB B tiles (swizzled)
    __shared__ float2 ringV[3][128];    // 3 x 1 KB {vc,lab} slices
    __shared__ float2 uband[512];       // band {u,lab}, staged per segment
    __shared__ float  sred[8];

    int bid  = blockIdx.x;
    int tid  = threadIdx.x;
    int w    = tid >> 6;
    int lane = tid & 63;

    // ================= phase 1: norm (32 rows/block) =================
    {
        float pospart = 0.f;
        int rbase = bid * 32 + w * 4;
        for (int r = 0; r < 4; ++r) {
            int row = rbase + r;
            int j   = pidx[row];
            float x  = emb[(size_t)row * DD + lane];
            float xj = emb[(size_t)j   * DD + lane];
            float n2  = wave_sum_f(x * x);
            float sx  = wave_sum_f(x);
            float n2j = wave_sum_f(xj * xj);
            float sxj = wave_sum_f(xj);
            float dot = wave_sum_f(x * xj);
            float m = fmaxf(sqrtf(n2), F_EPS_NORM);
            ebf[(size_t)row * DD + lane] = __float2bfloat16(x / m);
            if (lane == 0) {
                float mj  = fmaxf(sqrtf(n2j), F_EPS_NORM);
                float sq  = n2 / (m * m);
                float sqj = n2j / (mj * mj);
                float s   = sx / m;
                float sj  = sxj / mj;
                float g   = dot / (m * mj);
                float lf  = (float)lab[row];
                up[row]  = make_float2(sq + 2.0f * F_EPS_PD * s, lf);
                vcp[row] = make_float2(
                    sq - 2.0f * F_EPS_PD * s + (float)DD * F_EPS_PD * F_EPS_PD, lf);
                float d2p = sq + sqj - 2.0f * g + 2.0f * F_EPS_PD * (s - sj)
                          + (float)DD * F_EPS_PD * F_EPS_PD;
                pospart += fmaxf(d2p, 0.0f);
            }
        }
        if (lane == 0) sred[w] = pospart;
        __syncthreads();
        if (tid == 0) {
            float t = 0.f;
            #pragma unroll
            for (int i = 0; i < 8; ++i) t += sred[i];
            posP[bid] = t;
        }
    }

    // ---- grid barrier A: all norm writes visible everywhere ----
    __syncthreads();
    if (tid == 0) {
        __hip_atomic_fetch_add(&cnt[0], 1u, __ATOMIC_RELEASE,
                               __HIP_MEMORY_SCOPE_AGENT);
        while (__hip_atomic_load(&cnt[0], __ATOMIC_ACQUIRE,
                                 __HIP_MEMORY_SCOPE_AGENT) < NBLK)
            __builtin_amdgcn_s_sleep(16);
    }
    __syncthreads();

    // ================= phase 2: pair (R8 core) =================
    {
        const short* ebfs = (const short*)ebf;
        int lrow = lane & 15, lkh = lane >> 4;
        int c0s  = ((lkh)     ^ (lrow & 7)) * 8;   // swizzled K[0:32) chunk
        int c1s  = ((lkh + 4) ^ (lrow & 7)) * 8;   // swizzled K[32:64) chunk

        int ks = (int)(((long long)bid * NUNITS) / NBLK);
        int ke = (int)(((long long)(bid + 1) * NUNITS) / NBLK);

        int I = (int)((65.0f - sqrtf(4225.0f - 2.0f * (float)ks)) * 0.5f);
        I = I < 0 ? 0 : (I > NBI - 1 ? NBI - 1 : I);
        while (band_off(I) > ks) --I;
        while (I < NBI - 1 && band_off(I + 1) <= ks) ++I;

        float hacc = 0.0f;
        int u0 = ks;
        while (u0 < ke) {
            int bend = band_off(I + 1);
            int n    = (ke < bend ? ke : bend) - u0;
            int tj0  = 4 * I + (u0 - band_off(I));
            int rowbase = I * 512 + w * 64;
            int rt      = 4 * I + (w >> 1);

            bf16x8 a[4][2];
            #pragma unroll
            for (int s = 0; s < 4; ++s) {
                const short* ab = ebfs + (size_t)(rowbase + 16 * s + lrow) * DD + lkh * 8;
                a[s][0] = *(const bf16x8*)(ab);
                a[s][1] = *(const bf16x8*)(ab + 32);
            }
            if (w < 4)
                __builtin_amdgcn_global_load_lds(
                    (gu32_t*)(const void*)(up + (size_t)I * 512 + w * 128 + lane * 2),
                    (lu32_t*)(void*)(uband + w * 128), 16, 0, 0);
            stage_tile(ebfs, vcp, tj0, &ringB[0][0], &ringV[0][0], w, lane);
            if (n > 1)
                stage_tile(ebfs, vcp, tj0 + 1, &ringB[1][0], &ringV[1][0], w, lane);

            int sl = 0;
            for (int k = 0; k < n; ++k) {
                if (k + 1 < n) asm volatile("s_waitcnt vmcnt(3)" ::: "memory");
                else           asm volatile("s_waitcnt vmcnt(0)" ::: "memory");
                __builtin_amdgcn_s_barrier();
                __builtin_amdgcn_sched_barrier(0);
                int sl2 = (sl >= 1) ? sl - 1 : 2;
                if (k + 2 < n)
                    stage_tile(ebfs, vcp, tj0 + k + 2, &ringB[sl2][0], &ringV[sl2][0],
                               w, lane);

                int tj = tj0 + k;
                float wgt = (tj == rt) ? 1.0f : ((tj > rt) ? 2.0f : 0.0f);
                if (wgt != 0.0f) {
                    const short*  lb = &ringB[sl][0];
                    const float2* lv = &ringV[sl][0];
                    float hp = 0.0f;
                    #pragma unroll
                    for (int t = 0; t < 8; ++t) {
                        const short* rowp = lb + (t * 16 + lrow) * 64;
                        bf16x8 b0 = *(const bf16x8*)(rowp + c0s);
                        bf16x8 b1 = *(const bf16x8*)(rowp + c1s);
                        __builtin_amdgcn_s_setprio(1);
                        f32x4 c4[4];
                        #pragma unroll
                        for (int s = 0; s < 4; ++s) {
                            f32x4 z = {0.f, 0.f, 0.f, 0.f};
                            z = __builtin_amdgcn_mfma_f32_16x16x32_bf16(a[s][0], b0, z, 0, 0, 0);
                            z = __builtin_amdgcn_mfma_f32_16x16x32_bf16(a[s][1], b1, z, 0, 0, 0);
                            c4[s] = z;
                        }
                        __builtin_amdgcn_s_setprio(0);
                        float m0 = fmaxf(fmaxf(c4[0][0], c4[0][1]), fmaxf(c4[0][2], c4[0][3]));
                        float m1 = fmaxf(fmaxf(c4[1][0], c4[1][1]), fmaxf(c4[1][2], c4[1][3]));
                        float m2 = fmaxf(fmaxf(c4[2][0], c4[2][1]), fmaxf(c4[2][2], c4[2][3]));
                        float m3 = fmaxf(fmaxf(c4[3][0], c4[3][1]), fmaxf(c4[3][2], c4[3][3]));
                        float mx = fmaxf(fmaxf(m0, m1), fmaxf(m2, m3));
                        if (__any(mx > SCREEN_T)) {            // rare; LDS-only path
                            float2 vl = lv[t * 16 + lrow];
                            #pragma unroll
                            for (int s = 0; s < 4; ++s) {
                                #pragma unroll
                                for (int r = 0; r < 4; ++r) {
                                    float2 ul = uband[w * 64 + 16 * s + lkh * 4 + r];
                                    float d2 = fmaf(-2.0f, c4[s][r], ul.x + vl.x);
                                    float d  = sqrtf(fmaxf(d2, 1e-12f));
                                    float h  = fmaxf(1.0f - d, 0.0f);
                                    if (ul.y != vl.y) hp = fmaf(h, h, hp);
                                }
                            }
                        }
                    }
                    hacc = fmaf(wgt, hp, hacc);
                }
                sl = (sl + 1 == 3) ? 0 : sl + 1;
            }
            __builtin_amdgcn_s_barrier();
            __builtin_amdgcn_sched_barrier(0);
            u0 += n;
            ++I;
        }

        hacc = wave_sum_f(hacc);
        if (lane == 0) sred[w] = hacc;
        __syncthreads();
        if (tid == 0) {
            float tn = 0.f;
            #pragma unroll
            for (int i = 0; i < 8; ++i) tn += sred[i];
            negP[bid] = tn;
        }
    }

    // ---- barrier B: signal; only block 0 waits and reduces ----
    __syncthreads();
    if (tid == 0)
        __hip_atomic_fetch_add(&cnt[1], 1u, __ATOMIC_RELEASE,
                               __HIP_MEMORY_SCOPE_AGENT);
    if (bid != 0) return;
    if (tid == 0) {
        while (__hip_atomic_load(&cnt[1], __ATOMIC_ACQUIRE,
                                 __HIP_MEMORY_SCOPE_AGENT) < NBLK)
            __builtin_amdgcn_s_sleep(16);
    }
    __syncthreads();

    // ================= phase 3: reduce (block 0) =================
    {
        unsigned int (*hist)[1024] = (unsigned int (*)[1024])(&ringB[0][0]);
        for (int i = tid; i < 4096; i += 512) hist[i >> 10][i & 1023] = 0u;
        __syncthreads();
        const int4* lab4 = (const int4*)lab;
        for (int i = tid; i < NN / 4; i += 512) {
            int4 v = lab4[i];
            atomicAdd(&hist[w & 3][v.x & 1023], 1u);
            atomicAdd(&hist[w & 3][v.y & 1023], 1u);
            atomicAdd(&hist[w & 3][v.z & 1023], 1u);
            atomicAdd(&hist[w & 3][v.w & 1023], 1u);
        }
        __syncthreads();

        float ps = posP[tid];              // NBLK == 512 == blockDim
        float ns = negP[tid];
        unsigned long long sqc = 0;
        for (int i = tid; i < 1024; i += 512) {
            unsigned long long h = (unsigned long long)hist[0][i] + hist[1][i]
                                 + hist[2][i] + hist[3][i];
            sqc += h * h;
        }
        ps = wave_sum_f(ps);
        ns = wave_sum_f(ns);
        #pragma unroll
        for (int o = 32; o >= 1; o >>= 1) sqc += __shfl_xor(sqc, o);

        float* sp = (float*)&ringV[0][0];
        float* sn = sp + 8;
        unsigned long long* sc = (unsigned long long*)(sp + 16);
        if (lane == 0) { sp[w] = ps; sn[w] = ns; sc[w] = sqc; }
        __syncthreads();
        if (tid == 0) {
            float pos = 0.f, neg = 0.f;
            unsigned long long s2 = 0;
            #pragma unroll
            for (int i = 0; i < 8; ++i) { pos += sp[i]; neg += sn[i]; s2 += sc[i]; }
            unsigned long long nneg = (unsigned long long)NN * NN - s2;
            float ncomp = (float)((unsigned long long)NN + nneg);
            out[0] = (pos + neg) / ncomp;
        }
    }
}

// ---------------------------------------------------------------------------
// ws layout (bytes):
//   up   @ 0        : 131072  (float2[16384]: {u, label})
//   vcp  @ 131072   : 131072  (float2[16384]: {vc, label})
//   ebf  @ 262144   : 2097152
//   posP @ 2359296  : 2048    (NBLK floats)
//   negP @ 2361344  : 2048    (NBLK floats)
//   cnt  @ 2363392  : 8       (two barrier counters, memset to 0 each call)
//   total 2363400
// ---------------------------------------------------------------------------
extern "C" void kernel_launch(void* const* d_in, const int* in_sizes, int n_in,
                              void* d_out, int out_size, void* d_ws, size_t ws_size,
                              hipStream_t stream) {
    const float* emb = (const float*)d_in[0];
    const int* lab   = (const int*)d_in[1];
    const int* pidx  = (const int*)d_in[2];
    float* out = (float*)d_out;
    char* ws = (char*)d_ws;
    float2*         up   = (float2*)(ws);
    float2*         vcp  = (float2*)(ws + 131072);
    __hip_bfloat16* ebf  = (__hip_bfloat16*)(ws + 262144);
    float*          posP = (float*)(ws + 2359296);
    float*          negP = (float*)(ws + 2361344);
    unsigned int*   cnt  = (unsigned int*)(ws + 2363392);

    hipMemsetAsync(cnt, 0, 8, stream);
    fused_kernel<<<NBLK, 512, 0, stream>>>(emb, pidx, lab, up, vcp, ebf,
                                           posP, negP, cnt, out);
}

// Round 15
// 56.144 us; speedup vs baseline: 1.7959x; 1.7959x over previous
//
#include <hip/hip_runtime.h>
#include <hip/hip_bf16.h>

#define NN 16384
#define DD 64
#define NBI 16                 // 1024-row bands
#define NUNITS 1088            // sum_I (128 - 8I), I=0..15
#define NBLK 256               // 1 block/CU (59.1 KB LDS, 16 waves)
#define NPOSB (NN/4)
#define SCREEN_T 0.49f         // hinge>0 needs gram > ~0.5-3e-5; margin 1e-2

constexpr float F_EPS_PD   = 1e-6f;
constexpr float F_EPS_NORM = 1e-6f;

using bf16x8 = __attribute__((ext_vector_type(8))) short;
using f32x4  = __attribute__((ext_vector_type(4))) float;
typedef __attribute__((address_space(1))) const unsigned int gu32_t;
typedef __attribute__((address_space(3))) unsigned int       lu32_t;

__device__ __forceinline__ float wave_sum_f(float v) {
    #pragma unroll
    for (int o = 32; o >= 1; o >>= 1) v += __shfl_xor(v, o);
    return v;
}

// unit offset of band I: sum_{j<I}(128-8j) = 4I(33-I)
__device__ __forceinline__ int band_off(int I) { return 4 * I * (33 - I); }

// ---------------------------------------------------------------------------
// Kernel 1: per-row normalize + bf16 copy + packed {u,lab}/{vc,lab} + exact
// fp32 positive-pair loss.   d2(i,j) = u_i + vc_j - 2*gram(i,j)
// ---------------------------------------------------------------------------
__global__ __launch_bounds__(256) void norm_kernel(
    const float* __restrict__ emb, const int* __restrict__ pidx,
    const int* __restrict__ lab, float2* __restrict__ up,
    float2* __restrict__ vcp, __hip_bfloat16* __restrict__ ebf,
    float* __restrict__ posP) {
    int w    = threadIdx.x >> 6;
    int row  = blockIdx.x * 4 + w;
    int lane = threadIdx.x & 63;
    int j    = pidx[row];
    float x  = emb[(size_t)row * DD + lane];
    float xj = emb[(size_t)j   * DD + lane];

    float n2  = wave_sum_f(x * x);
    float sx  = wave_sum_f(x);
    float n2j = wave_sum_f(xj * xj);
    float sxj = wave_sum_f(xj);
    float dot = wave_sum_f(x * xj);

    float m  = fmaxf(sqrtf(n2),  F_EPS_NORM);
    float mj = fmaxf(sqrtf(n2j), F_EPS_NORM);
    ebf[(size_t)row * DD + lane] = __float2bfloat16(x / m);

    __shared__ float spos[4];
    if (lane == 0) {
        float sq  = n2 / (m * m);
        float sqj = n2j / (mj * mj);
        float s   = sx / m;
        float sj  = sxj / mj;
        float g   = dot / (m * mj);
        float lf  = (float)lab[row];
        up[row]  = make_float2(sq + 2.0f * F_EPS_PD * s, lf);
        vcp[row] = make_float2(
            sq - 2.0f * F_EPS_PD * s + (float)DD * F_EPS_PD * F_EPS_PD, lf);
        float d2p = sq + sqj - 2.0f * g + 2.0f * F_EPS_PD * (s - sj)
                  + (float)DD * F_EPS_PD * F_EPS_PD;
        spos[w] = fmaxf(d2p, 0.0f);
    }
    __syncthreads();
    if (threadIdx.x == 0)
        posP[blockIdx.x] = spos[0] + spos[1] + spos[2] + spos[3];
}

// ---------------------------------------------------------------------------
// Stage one (B tile 16 KB + vcp slice 1 KB) into a ring slot — 16-wave
// version: exactly 2 ops per wave (1 B-op covering rows 8w..8w+8, 1 redundant
// vcp op) -> uniform vmcnt counts. B source XOR-preswizzled (both-sides
// rule): LDS row r, 16B slot c holds global chunk c^(r&7); matching read-XOR
// applied in compute.
// ---------------------------------------------------------------------------
__device__ __forceinline__ void stage_tile(const short* ebf, const float2* vcp,
                                           int tile, short* slotB, float2* slotV,
                                           int w, int lane) {
    const short* tbase = ebf + (size_t)tile * (128 * DD);
    int rlo = lane >> 3;
    int g   = (lane & 7) ^ rlo;
    __builtin_amdgcn_global_load_lds(
        (gu32_t*)(const void*)(tbase + (size_t)(8 * w + rlo) * DD + g * 8),
        (lu32_t*)(void*)(slotB + w * 512), 16, 0, 0);
    __builtin_amdgcn_global_load_lds(
        (gu32_t*)(const void*)(vcp + (size_t)tile * 128 + lane * 2),
        (lu32_t*)(void*)slotV, 16, 0, 0);
}

// ---------------------------------------------------------------------------
// Kernel 2: 16-wave blocks over (1024-row band I, 128-col tile tj), tj>=8I.
// R15: double MFMA-per-staged-tile vs R8 (1024 MFMA / 16 KB stage) to test
// the fixed-per-round-cost theory; rounds/CU halve 8.25 -> 4.25.
// Counted-vmcnt 3-slot ring, 2-deep prefetch: steady wait vmcnt(2) (own
// 2 ops of tile k drained; tile k+1's 2 newest in flight), last vmcnt(0).
// Zero vmem in compute (rare path reads uband/ringV LDS only).
// Per-wave inner code identical to R8: wave owns 64 rows (4 strips).
// ---------------------------------------------------------------------------
__global__ __launch_bounds__(1024, 4) void pair_kernel(
    const short* __restrict__ ebf, const float2* __restrict__ up,
    const float2* __restrict__ vcp, float* __restrict__ negP) {
    __shared__ short  ringB[3][8192];   // 3 x 16 KB B tiles (swizzled)
    __shared__ float2 ringV[3][128];    // 3 x 1 KB {vc,lab} slices
    __shared__ float2 uband[1024];      // band {u,lab}, staged per segment
    __shared__ float  sred[16];
    int tid  = threadIdx.x;
    int w    = tid >> 6;
    int lane = tid & 63;
    int lrow = lane & 15, lkh = lane >> 4;
    int c0s  = ((lkh)     ^ (lrow & 7)) * 8;   // swizzled K[0:32) chunk
    int c1s  = ((lkh + 4) ^ (lrow & 7)) * 8;   // swizzled K[32:64) chunk

    int ks = (int)(((long long)blockIdx.x * NUNITS) / NBLK);
    int ke = (int)(((long long)(blockIdx.x + 1) * NUNITS) / NBLK);

    // decode ks -> band I  (band_off(I) = 4I(33-I))
    int I = (int)((33.0f - sqrtf(1089.0f - (float)ks)) * 0.5f);
    I = I < 0 ? 0 : (I > NBI - 1 ? NBI - 1 : I);
    while (band_off(I) > ks) --I;
    while (I < NBI - 1 && band_off(I + 1) <= ks) ++I;

    float hacc = 0.0f;
    int u0 = ks;
    while (u0 < ke) {
        int bend = band_off(I + 1);
        int n    = (ke < bend ? ke : bend) - u0;
        int tj0  = 8 * I + (u0 - band_off(I));
        int rowbase = I * 1024 + w * 64;
        int rt      = 8 * I + (w >> 1);

        // --- segment prologue: A frags, u-band stage, prime 2 tiles ---
        bf16x8 a[4][2];
        #pragma unroll
        for (int s = 0; s < 4; ++s) {
            const short* ab = ebf + (size_t)(rowbase + 16 * s + lrow) * DD + lkh * 8;
            a[s][0] = *(const bf16x8*)(ab);
            a[s][1] = *(const bf16x8*)(ab + 32);
        }
        if (w < 8)
            __builtin_amdgcn_global_load_lds(
                (gu32_t*)(const void*)(up + (size_t)I * 1024 + w * 128 + lane * 2),
                (lu32_t*)(void*)(uband + w * 128), 16, 0, 0);
        stage_tile(ebf, vcp, tj0, &ringB[0][0], &ringV[0][0], w, lane);
        if (n > 1)
            stage_tile(ebf, vcp, tj0 + 1, &ringB[1][0], &ringV[1][0], w, lane);

        int sl = 0;                        // ring slot of tile k
        for (int k = 0; k < n; ++k) {
            // steady: own 2 ops of tile k drained; tile k+1 (2 newest) in flight
            if (k + 1 < n) asm volatile("s_waitcnt vmcnt(2)" ::: "memory");
            else           asm volatile("s_waitcnt vmcnt(0)" ::: "memory");
            __builtin_amdgcn_s_barrier();
            __builtin_amdgcn_sched_barrier(0);
            int sl2 = (sl >= 1) ? sl - 1 : 2;     // slot of tile k+2
            if (k + 2 < n)
                stage_tile(ebf, vcp, tj0 + k + 2, &ringB[sl2][0], &ringV[sl2][0],
                           w, lane);

            int tj = tj0 + k;
            float wgt = (tj == rt) ? 1.0f : ((tj > rt) ? 2.0f : 0.0f);
            if (wgt != 0.0f) {
                const short*  lb = &ringB[sl][0];
                const float2* lv = &ringV[sl][0];
                float hp = 0.0f;
                #pragma unroll
                for (int t = 0; t < 8; ++t) {
                    const short* rowp = lb + (t * 16 + lrow) * 64;
                    bf16x8 b0 = *(const bf16x8*)(rowp + c0s);
                    bf16x8 b1 = *(const bf16x8*)(rowp + c1s);
                    __builtin_amdgcn_s_setprio(1);
                    f32x4 c4[4];
                    #pragma unroll
                    for (int s = 0; s < 4; ++s) {
                        f32x4 z = {0.f, 0.f, 0.f, 0.f};
                        z = __builtin_amdgcn_mfma_f32_16x16x32_bf16(a[s][0], b0, z, 0, 0, 0);
                        z = __builtin_amdgcn_mfma_f32_16x16x32_bf16(a[s][1], b1, z, 0, 0, 0);
                        c4[s] = z;
                    }
                    __builtin_amdgcn_s_setprio(0);
                    float m0 = fmaxf(fmaxf(c4[0][0], c4[0][1]), fmaxf(c4[0][2], c4[0][3]));
                    float m1 = fmaxf(fmaxf(c4[1][0], c4[1][1]), fmaxf(c4[1][2], c4[1][3]));
                    float m2 = fmaxf(fmaxf(c4[2][0], c4[2][1]), fmaxf(c4[2][2], c4[2][3]));
                    float m3 = fmaxf(fmaxf(c4[3][0], c4[3][1]), fmaxf(c4[3][2], c4[3][3]));
                    float mx = fmaxf(fmaxf(m0, m1), fmaxf(m2, m3));
                    if (__any(mx > SCREEN_T)) {            // rare; LDS-only path
                        float2 vl = lv[t * 16 + lrow];
                        #pragma unroll
                        for (int s = 0; s < 4; ++s) {
                            #pragma unroll
                            for (int r = 0; r < 4; ++r) {
                                float2 ul = uband[w * 64 + 16 * s + lkh * 4 + r];
                                float d2 = fmaf(-2.0f, c4[s][r], ul.x + vl.x);
                                float d  = sqrtf(fmaxf(d2, 1e-12f));
                                float h  = fmaxf(1.0f - d, 0.0f);
                                if (ul.y != vl.y) hp = fmaf(h, h, hp);
                            }
                        }
                    }
                }
                hacc = fmaf(wgt, hp, hacc);
            }
            sl = (sl + 1 == 3) ? 0 : sl + 1;
        }
        __builtin_amdgcn_s_barrier();      // protect ring/uband reuse
        __builtin_amdgcn_sched_barrier(0);
        u0 += n;
        ++I;
    }

    hacc = wave_sum_f(hacc);
    if (lane == 0) sred[w] = hacc;
    __syncthreads();
    if (tid == 0) {
        float tn = 0.f;
        #pragma unroll
        for (int i = 0; i < 16; ++i) tn += sred[i];
        negP[blockIdx.x] = tn;
    }
}

// ---------------------------------------------------------------------------
// Kernel 3: final reduction + 4-replica label histogram -> analytic negative
// count: n_neg = N^2 - sum_c n_c^2 ; n_comparisons = N + n_neg
// ---------------------------------------------------------------------------
__global__ __launch_bounds__(1024) void reduce_kernel(
    const float* __restrict__ posP, const float* __restrict__ negP,
    const int* __restrict__ lab, float* __restrict__ out) {
    __shared__ unsigned int hist[4][1024];
    int t = threadIdx.x;
    int w = t >> 6, lane = t & 63;
    for (int i = t; i < 4096; i += 1024) hist[i >> 10][i & 1023] = 0u;
    __syncthreads();
    const int4* lab4 = (const int4*)lab;
    for (int i = t; i < NN / 4; i += 1024) {
        int4 v = lab4[i];
        atomicAdd(&hist[w & 3][v.x & 1023], 1u);
        atomicAdd(&hist[w & 3][v.y & 1023], 1u);
        atomicAdd(&hist[w & 3][v.z & 1023], 1u);
        atomicAdd(&hist[w & 3][v.w & 1023], 1u);
    }
    __syncthreads();

    float ps = 0.f, ns = 0.f;
    unsigned long long sqc = 0u;
    const float4* posP4 = (const float4*)posP;
    for (int i = t; i < NPOSB / 4; i += 1024) {
        float4 v = posP4[i];
        ps += (v.x + v.y) + (v.z + v.w);
    }
    if (t < NBLK) ns = negP[t];
    {
        unsigned long long h = (unsigned long long)hist[0][t & 1023] + hist[1][t & 1023]
                             + hist[2][t & 1023] + hist[3][t & 1023];
        sqc = h * h;
    }

    ps = wave_sum_f(ps);
    ns = wave_sum_f(ns);
    #pragma unroll
    for (int o = 32; o >= 1; o >>= 1) sqc += __shfl_xor(sqc, o);

    __shared__ float sp[16], sn[16];
    __shared__ unsigned long long sc[16];
    if (lane == 0) { sp[w] = ps; sn[w] = ns; sc[w] = sqc; }
    __syncthreads();
    if (t == 0) {
        float pos = 0.f, neg = 0.f;
        unsigned long long s2 = 0;
        #pragma unroll
        for (int i = 0; i < 16; ++i) { pos += sp[i]; neg += sn[i]; s2 += sc[i]; }
        unsigned long long nneg = (unsigned long long)NN * NN - s2;
        float ncomp = (float)((unsigned long long)NN + nneg);
        out[0] = (pos + neg) / ncomp;
    }
}

// ---------------------------------------------------------------------------
// ws layout (bytes):
//   up   @ 0        : 131072  (float2[16384]: {u, label})
//   vcp  @ 131072   : 131072  (float2[16384]: {vc, label})
//   ebf  @ 262144   : 2097152
//   posP @ 2359296  : 16384   (NPOSB floats)
//   negP @ 2375680  : 1024    (NBLK=256 floats)
//   total 2376704
// ---------------------------------------------------------------------------
extern "C" void kernel_launch(void* const* d_in, const int* in_sizes, int n_in,
                              void* d_out, int out_size, void* d_ws, size_t ws_size,
                              hipStream_t stream) {
    const float* emb = (const float*)d_in[0];
    const int* lab   = (const int*)d_in[1];
    const int* pidx  = (const int*)d_in[2];
    float* out = (float*)d_out;
    char* ws = (char*)d_ws;
    float2*         up   = (float2*)(ws);
    float2*         vcp  = (float2*)(ws + 131072);
    __hip_bfloat16* ebf  = (__hip_bfloat16*)(ws + 262144);
    float*          posP = (float*)(ws + 2359296);
    float*          negP = (float*)(ws + 2375680);

    norm_kernel<<<NPOSB, 256, 0, stream>>>(emb, pidx, lab, up, vcp, ebf, posP);
    pair_kernel<<<NBLK, 1024, 0, stream>>>((const short*)ebf, up, vcp, negP);
    reduce_kernel<<<1, 1024, 0, stream>>>(posP, negP, lab, out);
}

// Round 16
// 52.769 us; speedup vs baseline: 1.9108x; 1.0640x over previous
//
#include <hip/hip_runtime.h>
#include <hip/hip_bf16.h>

#define NN 16384
#define DD 64
#define NBI 32                 // 512-row bands
#define NUNITS 2112            // sum_I (128 - 4I), I=0..31
#define NBLK 512               // 2 blocks/CU (56.4 KB LDS)
#define NPOSB (NN/4)
#define SCREEN_T 0.49f         // hinge>0 needs gram > ~0.5-3e-5; margin 1e-2

constexpr float F_EPS_PD   = 1e-6f;
constexpr float F_EPS_NORM = 1e-6f;

using bf16x8 = __attribute__((ext_vector_type(8))) short;
using f32x4  = __attribute__((ext_vector_type(4))) float;
typedef __attribute__((address_space(1))) const unsigned int gu32_t;
typedef __attribute__((address_space(3))) unsigned int       lu32_t;

__device__ __forceinline__ float wave_sum_f(float v) {
    #pragma unroll
    for (int o = 32; o >= 1; o >>= 1) v += __shfl_xor(v, o);
    return v;
}

__device__ __forceinline__ int band_off(int I) { return 2 * I * (65 - I); }

// ---------------------------------------------------------------------------
// Kernel 1: per-row normalize + bf16 copy + packed {u,lab}/{vc,lab} + exact
// fp32 positive-pair loss.   d2(i,j) = u_i + vc_j - 2*gram(i,j)
// ---------------------------------------------------------------------------
__global__ __launch_bounds__(256) void norm_kernel(
    const float* __restrict__ emb, const int* __restrict__ pidx,
    const int* __restrict__ lab, float2* __restrict__ up,
    float2* __restrict__ vcp, __hip_bfloat16* __restrict__ ebf,
    float* __restrict__ posP) {
    int w    = threadIdx.x >> 6;
    int row  = blockIdx.x * 4 + w;
    int lane = threadIdx.x & 63;
    int j    = pidx[row];
    float x  = emb[(size_t)row * DD + lane];
    float xj = emb[(size_t)j   * DD + lane];

    float n2  = wave_sum_f(x * x);
    float sx  = wave_sum_f(x);
    float n2j = wave_sum_f(xj * xj);
    float sxj = wave_sum_f(xj);
    float dot = wave_sum_f(x * xj);

    float m  = fmaxf(sqrtf(n2),  F_EPS_NORM);
    float mj = fmaxf(sqrtf(n2j), F_EPS_NORM);
    ebf[(size_t)row * DD + lane] = __float2bfloat16(x / m);

    __shared__ float spos[4];
    if (lane == 0) {
        float sq  = n2 / (m * m);
        float sqj = n2j / (mj * mj);
        float s   = sx / m;
        float sj  = sxj / mj;
        float g   = dot / (m * mj);
        float lf  = (float)lab[row];
        up[row]  = make_float2(sq + 2.0f * F_EPS_PD * s, lf);
        vcp[row] = make_float2(
            sq - 2.0f * F_EPS_PD * s + (float)DD * F_EPS_PD * F_EPS_PD, lf);
        float d2p = sq + sqj - 2.0f * g + 2.0f * F_EPS_PD * (s - sj)
                  + (float)DD * F_EPS_PD * F_EPS_PD;
        spos[w] = fmaxf(d2p, 0.0f);
    }
    __syncthreads();
    if (threadIdx.x == 0)
        posP[blockIdx.x] = spos[0] + spos[1] + spos[2] + spos[3];
}

// ---------------------------------------------------------------------------
// Stage one (B tile 16 KB + vcp slice 1 KB) into a ring slot. 3 ops per wave
// (uniform -> exact vmcnt counts). B source XOR-preswizzled (both-sides rule).
// ---------------------------------------------------------------------------
__device__ __forceinline__ void stage_tile(const short* ebf, const float2* vcp,
                                           int tile, short* slotB, float2* slotV,
                                           int w, int lane) {
    const short* tbase = ebf + (size_t)tile * (128 * DD);
    int rlo = lane >> 3;
    int g   = (lane & 7) ^ rlo;
    #pragma unroll
    for (int q = 0; q < 2; ++q) {
        int m = w * 2 + q;
        __builtin_amdgcn_global_load_lds(
            (gu32_t*)(const void*)(tbase + (size_t)(8 * m + rlo) * DD + g * 8),
            (lu32_t*)(void*)(slotB + m * 512), 16, 0, 0);
    }
    __builtin_amdgcn_global_load_lds(
        (gu32_t*)(const void*)(vcp + (size_t)tile * 128 + lane * 2),
        (lu32_t*)(void*)slotV, 16, 0, 0);
}

// ---------------------------------------------------------------------------
// Kernel 2: R8 champion skeleton (counted-vmcnt 3-slot ring, 2-deep prefetch,
// zero vmem in compute) with TWO changes (R16):
//  (a) __launch_bounds__(512, 2): VGPR budget ~128 (LDS still caps blocks/CU
//      at 2 -> 16 waves/CU unchanged). R8's (512,4) held VGPR at 48-52 =
//      a[32]+c4[16] with ZERO B-prefetch headroom -> serial ds_read->MFMA
//      chains, ~150-250 cy exposed LDS latency per t-iter (the ~30 us gap).
//  (b) quarter-tile register pipeline: named B-buffers Q0/Q1 (static idx,
//      rule #20); issue ds_reads for quarter q+1 BEFORE computing quarter q
//      -> each quarter's reads hide under ~180 cy of MFMA+screen issue.
// ---------------------------------------------------------------------------
#define LOADQ(B, t0_)                                                          \
    do {                                                                       \
        const short* r0_ = lb + ((t0_) * 16 + lrow) * 64;                      \
        const short* r1_ = lb + (((t0_) + 1) * 16 + lrow) * 64;                \
        B[0][0] = *(const bf16x8*)(r0_ + c0s);                                 \
        B[0][1] = *(const bf16x8*)(r0_ + c1s);                                 \
        B[1][0] = *(const bf16x8*)(r1_ + c0s);                                 \
        B[1][1] = *(const bf16x8*)(r1_ + c1s);                                 \
    } while (0)

#define COMPQ(B, t0_)                                                          \
    do {                                                                       \
        _Pragma("unroll")                                                      \
        for (int tt_ = 0; tt_ < 2; ++tt_) {                                    \
            __builtin_amdgcn_s_setprio(1);                                     \
            f32x4 c4[4];                                                       \
            _Pragma("unroll")                                                  \
            for (int s_ = 0; s_ < 4; ++s_) {                                   \
                f32x4 z_ = {0.f, 0.f, 0.f, 0.f};                               \
                z_ = __builtin_amdgcn_mfma_f32_16x16x32_bf16(a[s_][0], B[tt_][0], z_, 0, 0, 0); \
                z_ = __builtin_amdgcn_mfma_f32_16x16x32_bf16(a[s_][1], B[tt_][1], z_, 0, 0, 0); \
                c4[s_] = z_;                                                   \
            }                                                                  \
            __builtin_amdgcn_s_setprio(0);                                     \
            float m0_ = fmaxf(fmaxf(c4[0][0], c4[0][1]), fmaxf(c4[0][2], c4[0][3])); \
            float m1_ = fmaxf(fmaxf(c4[1][0], c4[1][1]), fmaxf(c4[1][2], c4[1][3])); \
            float m2_ = fmaxf(fmaxf(c4[2][0], c4[2][1]), fmaxf(c4[2][2], c4[2][3])); \
            float m3_ = fmaxf(fmaxf(c4[3][0], c4[3][1]), fmaxf(c4[3][2], c4[3][3])); \
            float mx_ = fmaxf(fmaxf(m0_, m1_), fmaxf(m2_, m3_));               \
            if (__any(mx_ > SCREEN_T)) {            /* rare; LDS-only path */  \
                float2 vl_ = lv[((t0_) + tt_) * 16 + lrow];                    \
                _Pragma("unroll")                                              \
                for (int s_ = 0; s_ < 4; ++s_) {                               \
                    _Pragma("unroll")                                          \
                    for (int r_ = 0; r_ < 4; ++r_) {                           \
                        float2 ul_ = uband[w * 64 + 16 * s_ + lkh * 4 + r_];   \
                        float d2_ = fmaf(-2.0f, c4[s_][r_], ul_.x + vl_.x);    \
                        float d_  = sqrtf(fmaxf(d2_, 1e-12f));                 \
                        float h_  = fmaxf(1.0f - d_, 0.0f);                    \
                        if (ul_.y != vl_.y) hp = fmaf(h_, h_, hp);             \
                    }                                                          \
                }                                                              \
            }                                                                  \
        }                                                                      \
    } while (0)

__global__ __launch_bounds__(512, 2) void pair_kernel(
    const short* __restrict__ ebf, const float2* __restrict__ up,
    const float2* __restrict__ vcp, float* __restrict__ negP) {
    __shared__ short  ringB[3][8192];   // 3 x 16 KB B tiles (swizzled)
    __shared__ float2 ringV[3][128];    // 3 x 1 KB {vc,lab} slices
    __shared__ float2 uband[512];       // band {u,lab}, staged per segment
    __shared__ float  sred[8];
    int tid  = threadIdx.x;
    int w    = tid >> 6;
    int lane = tid & 63;
    int lrow = lane & 15, lkh = lane >> 4;
    int c0s  = ((lkh)     ^ (lrow & 7)) * 8;   // swizzled K[0:32) chunk
    int c1s  = ((lkh + 4) ^ (lrow & 7)) * 8;   // swizzled K[32:64) chunk

    int ks = (int)(((long long)blockIdx.x * NUNITS) / NBLK);
    int ke = (int)(((long long)(blockIdx.x + 1) * NUNITS) / NBLK);

    // decode ks -> band I
    int I = (int)((65.0f - sqrtf(4225.0f - 2.0f * (float)ks)) * 0.5f);
    I = I < 0 ? 0 : (I > NBI - 1 ? NBI - 1 : I);
    while (band_off(I) > ks) --I;
    while (I < NBI - 1 && band_off(I + 1) <= ks) ++I;

    float hacc = 0.0f;
    int u0 = ks;
    while (u0 < ke) {
        int bend = band_off(I + 1);
        int n    = (ke < bend ? ke : bend) - u0;
        int tj0  = 4 * I + (u0 - band_off(I));
        int rowbase = I * 512 + w * 64;
        int rt      = 4 * I + (w >> 1);

        // --- segment prologue: A frags, u-band stage, prime 2 tiles ---
        bf16x8 a[4][2];
        #pragma unroll
        for (int s = 0; s < 4; ++s) {
            const short* ab = ebf + (size_t)(rowbase + 16 * s + lrow) * DD + lkh * 8;
            a[s][0] = *(const bf16x8*)(ab);
            a[s][1] = *(const bf16x8*)(ab + 32);
        }
        if (w < 4)
            __builtin_amdgcn_global_load_lds(
                (gu32_t*)(const void*)(up + (size_t)I * 512 + w * 128 + lane * 2),
                (lu32_t*)(void*)(uband + w * 128), 16, 0, 0);
        stage_tile(ebf, vcp, tj0, &ringB[0][0], &ringV[0][0], w, lane);
        if (n > 1)
            stage_tile(ebf, vcp, tj0 + 1, &ringB[1][0], &ringV[1][0], w, lane);

        int sl = 0;                        // ring slot of tile k
        for (int k = 0; k < n; ++k) {
            if (k + 1 < n) asm volatile("s_waitcnt vmcnt(3)" ::: "memory");
            else           asm volatile("s_waitcnt vmcnt(0)" ::: "memory");
            __builtin_amdgcn_s_barrier();
            __builtin_amdgcn_sched_barrier(0);
            int sl2 = (sl >= 1) ? sl - 1 : 2;     // slot of tile k+2
            if (k + 2 < n)
                stage_tile(ebf, vcp, tj0 + k + 2, &ringB[sl2][0], &ringV[sl2][0],
                           w, lane);

            int tj = tj0 + k;
            float wgt = (tj == rt) ? 1.0f : ((tj > rt) ? 2.0f : 0.0f);
            if (wgt != 0.0f) {
                const short*  lb = &ringB[sl][0];
                const float2* lv = &ringV[sl][0];
                float hp = 0.0f;
                bf16x8 Q0[2][2], Q1[2][2];
                // quarter-pipelined: reads of q+1 issue before compute of q
                LOADQ(Q0, 0);
                LOADQ(Q1, 2);
                COMPQ(Q0, 0);
                LOADQ(Q0, 4);
                COMPQ(Q1, 2);
                LOADQ(Q1, 6);
                COMPQ(Q0, 4);
                COMPQ(Q1, 6);
                hacc = fmaf(wgt, hp, hacc);
            }
            sl = (sl + 1 == 3) ? 0 : sl + 1;
        }
        __builtin_amdgcn_s_barrier();      // protect ring/uband reuse
        __builtin_amdgcn_sched_barrier(0);
        u0 += n;
        ++I;
    }

    hacc = wave_sum_f(hacc);
    if (lane == 0) sred[w] = hacc;
    __syncthreads();
    if (tid == 0) {
        float tn = 0.f;
        #pragma unroll
        for (int i = 0; i < 8; ++i) tn += sred[i];
        negP[blockIdx.x] = tn;
    }
}

// ---------------------------------------------------------------------------
// Kernel 3: final reduction + 4-replica label histogram -> analytic negative
// count: n_neg = N^2 - sum_c n_c^2 ; n_comparisons = N + n_neg
// ---------------------------------------------------------------------------
__global__ __launch_bounds__(1024) void reduce_kernel(
    const float* __restrict__ posP, const float* __restrict__ negP,
    const int* __restrict__ lab, float* __restrict__ out) {
    __shared__ unsigned int hist[4][1024];
    int t = threadIdx.x;
    int w = t >> 6, lane = t & 63;
    for (int i = t; i < 4096; i += 1024) hist[i >> 10][i & 1023] = 0u;
    __syncthreads();
    const int4* lab4 = (const int4*)lab;
    for (int i = t; i < NN / 4; i += 1024) {
        int4 v = lab4[i];
        atomicAdd(&hist[w & 3][v.x & 1023], 1u);
        atomicAdd(&hist[w & 3][v.y & 1023], 1u);
        atomicAdd(&hist[w & 3][v.z & 1023], 1u);
        atomicAdd(&hist[w & 3][v.w & 1023], 1u);
    }
    __syncthreads();

    float ps = 0.f, ns = 0.f;
    unsigned long long sqc = 0u;
    const float4* posP4 = (const float4*)posP;
    for (int i = t; i < NPOSB / 4; i += 1024) {
        float4 v = posP4[i];
        ps += (v.x + v.y) + (v.z + v.w);
    }
    if (t < NBLK) ns = negP[t];
    {
        unsigned long long h = (unsigned long long)hist[0][t & 1023] + hist[1][t & 1023]
                             + hist[2][t & 1023] + hist[3][t & 1023];
        sqc = h * h;
    }

    ps = wave_sum_f(ps);
    ns = wave_sum_f(ns);
    #pragma unroll
    for (int o = 32; o >= 1; o >>= 1) sqc += __shfl_xor(sqc, o);

    __shared__ float sp[16], sn[16];
    __shared__ unsigned long long sc[16];
    if (lane == 0) { sp[w] = ps; sn[w] = ns; sc[w] = sqc; }
    __syncthreads();
    if (t == 0) {
        float pos = 0.f, neg = 0.f;
        unsigned long long s2 = 0;
        #pragma unroll
        for (int i = 0; i < 16; ++i) { pos += sp[i]; neg += sn[i]; s2 += sc[i]; }
        unsigned long long nneg = (unsigned long long)NN * NN - s2;
        float ncomp = (float)((unsigned long long)NN + nneg);
        out[0] = (pos + neg) / ncomp;
    }
}

// ---------------------------------------------------------------------------
// ws layout (bytes):
//   up   @ 0        : 131072  (float2[16384]: {u, label})
//   vcp  @ 131072   : 131072  (float2[16384]: {vc, label})
//   ebf  @ 262144   : 2097152
//   posP @ 2359296  : 16384   (NPOSB floats)
//   negP @ 2375680  : 2048    (NBLK=512 floats)
//   total 2377728
// ---------------------------------------------------------------------------
extern "C" void kernel_launch(void* const* d_in, const int* in_sizes, int n_in,
                              void* d_out, int out_size, void* d_ws, size_t ws_size,
                              hipStream_t stream) {
    const float* emb = (const float*)d_in[0];
    const int* lab   = (const int*)d_in[1];
    const int* pidx  = (const int*)d_in[2];
    float* out = (float*)d_out;
    char* ws = (char*)d_ws;
    float2*         up   = (float2*)(ws);
    float2*         vcp  = (float2*)(ws + 131072);
    __hip_bfloat16* ebf  = (__hip_bfloat16*)(ws + 262144);
    float*          posP = (float*)(ws + 2359296);
    float*          negP = (float*)(ws + 2375680);

    norm_kernel<<<NPOSB, 256, 0, stream>>>(emb, pidx, lab, up, vcp, ebf, posP);
    pair_kernel<<<NBLK, 512, 0, stream>>>((const short*)ebf, up, vcp, negP);
    reduce_kernel<<<1, 1024, 0, stream>>>(posP, negP, lab, out);
}